// Round 9
// baseline (305.661 us; speedup 1.0000x reference)
//
#include <hip/hip_runtime.h>

#define PD(i) ((i) + ((i) >> 5))   // LDS pad (init FFT only)
#define BLD 524288                 // 8*2048*32

__device__ __forceinline__ float2 cadd(float2 a, float2 b){ return make_float2(a.x+b.x, a.y+b.y); }
__device__ __forceinline__ float2 csub(float2 a, float2 b){ return make_float2(a.x-b.x, a.y-b.y); }
__device__ __forceinline__ float2 cmul(float2 a, float2 b){ return make_float2(a.x*b.x - a.y*b.y, a.x*b.y + a.y*b.x); }
__device__ __forceinline__ float2 cmuli(float2 a, float s){ return make_float2(-s*a.y, s*a.x); }

// DPP wave64 sum; lane 63 holds the total.
template<int CTRL, int RM>
__device__ __forceinline__ float dpp_add(float x){
  int r = __builtin_amdgcn_update_dpp(0, __float_as_int(x), CTRL, RM, 0xf, true);
  return x + __int_as_float(r);
}
__device__ __forceinline__ float wave_sum64(float x){
  x = dpp_add<0x111,0xf>(x);
  x = dpp_add<0x112,0xf>(x);
  x = dpp_add<0x114,0xf>(x);
  x = dpp_add<0x118,0xf>(x);
  x = dpp_add<0x142,0xa>(x);
  x = dpp_add<0x143,0xc>(x);
  return x;
}

// cross-lane exchange helpers (wave64)
__device__ __forceinline__ float2 exbp(int addr, float2 v){
  return make_float2(
    __int_as_float(__builtin_amdgcn_ds_bpermute(addr, __float_as_int(v.x))),
    __int_as_float(__builtin_amdgcn_ds_bpermute(addr, __float_as_int(v.y))));
}
template<int PAT>
__device__ __forceinline__ float2 exswz(float2 v){
  return make_float2(
    __int_as_float(__builtin_amdgcn_ds_swizzle(__float_as_int(v.x), PAT)),
    __int_as_float(__builtin_amdgcn_ds_swizzle(__float_as_int(v.y), PAT)));
}
template<int CTRL>
__device__ __forceinline__ float2 exdpp(float2 v){
  return make_float2(
    __int_as_float(__builtin_amdgcn_update_dpp(0, __float_as_int(v.x), CTRL, 0xF, 0xF, true)),
    __int_as_float(__builtin_amdgcn_update_dpp(0, __float_as_int(v.y), CTRL, 0xF, 0xF, true)));
}

// DFT-8 (init FFT only)
template<int SGN>
__device__ __forceinline__ void dft8(float2 a[8]) {
  const float sgn = (float)SGN;
  const float C8 = 0.70710678118654752440f;
  float2 e0=a[0], e1=a[2], e2=a[4], e3=a[6];
  float2 o0=a[1], o1=a[3], o2=a[5], o3=a[7];
  float2 t0=cadd(e0,e2), t1=csub(e0,e2), t2=cadd(e1,e3), t3=csub(e1,e3);
  float2 E0=cadd(t0,t2), E2=csub(t0,t2);
  float2 t3i=cmuli(t3,sgn);
  float2 E1=cadd(t1,t3i), E3=csub(t1,t3i);
  float2 s0=cadd(o0,o2), s1=csub(o0,o2), s2=cadd(o1,o3), s3=csub(o1,o3);
  float2 O0=cadd(s0,s2), O2=csub(s0,s2);
  float2 s3i=cmuli(s3,sgn);
  float2 O1=cadd(s1,s3i), O3=csub(s1,s3i);
  float2 w1o = make_float2(C8*(O1.x - sgn*O1.y), C8*(O1.y + sgn*O1.x));
  float2 w2o = cmuli(O2, sgn);
  float2 w3o = make_float2(-C8*(O3.x + sgn*O3.y), C8*(sgn*O3.x - O3.y));
  a[0]=cadd(E0,O0); a[4]=csub(E0,O0);
  a[1]=cadd(E1,w1o); a[5]=csub(E1,w1o);
  a[2]=cadd(E2,w2o); a[6]=csub(E2,w2o);
  a[3]=cadd(E3,w3o); a[7]=csub(E3,w3o);
}

// Init-only 2048-pt Stockham FFT (radix 8,8,8,4), natural order, result in bufA.
template<int SGN>
__device__ void fft2048(float2* bufA, float2* bufB, const float2* twd, int tid)
{
  const float sgn = (float)SGN;
  {
    float2 a[8];
    #pragma unroll
    for (int j=0;j<8;j++) a[j] = bufA[PD(tid + 256*j)];
    dft8<SGN>(a);
    float2 tw = twd[tid];
    float2 w1 = make_float2(tw.x, sgn*tw.y), wj = w1;
    #pragma unroll
    for (int j=1;j<8;j++){ a[j] = cmul(a[j], wj); wj = cmul(wj, w1); }
    #pragma unroll
    for (int j=0;j<8;j++) bufB[PD(8*tid + j)] = a[j];
  }
  __syncthreads();
  {
    float2 a[8];
    #pragma unroll
    for (int j=0;j<8;j++) a[j] = bufB[PD(tid + 256*j)];
    dft8<SGN>(a);
    int p = tid >> 3, q = tid & 7;
    float2 tw = twd[p << 3];
    float2 w1 = make_float2(tw.x, sgn*tw.y), wj = w1;
    #pragma unroll
    for (int j=1;j<8;j++){ a[j] = cmul(a[j], wj); wj = cmul(wj, w1); }
    int base = q + (p << 6);
    #pragma unroll
    for (int j=0;j<8;j++) bufA[PD(base + (j<<3))] = a[j];
  }
  __syncthreads();
  {
    float2 a[8];
    #pragma unroll
    for (int j=0;j<8;j++) a[j] = bufA[PD(tid + 256*j)];
    dft8<SGN>(a);
    int p = tid >> 6, q = tid & 63;
    float2 tw = twd[p << 6];
    float2 w1 = make_float2(tw.x, sgn*tw.y), wj = w1;
    #pragma unroll
    for (int j=1;j<8;j++){ a[j] = cmul(a[j], wj); wj = cmul(wj, w1); }
    int base = q + (p << 9);
    #pragma unroll
    for (int j=0;j<8;j++) bufB[PD(base + (j<<6))] = a[j];
  }
  __syncthreads();
  {
    #pragma unroll
    for (int h=0; h<2; h++){
      int q = tid + (h<<8);
      float2 b0 = bufB[PD(q)], b1 = bufB[PD(q+512)], b2 = bufB[PD(q+1024)], b3 = bufB[PD(q+1536)];
      float2 t0=cadd(b0,b2), t1=csub(b0,b2), t2=cadd(b1,b3), t3=csub(b1,b3);
      float2 t3i=cmuli(t3,sgn);
      bufA[PD(q)]      = cadd(t0,t2);
      bufA[PD(q+512)]  = cadd(t1,t3i);
      bufA[PD(q+1024)] = csub(t0,t2);
      bufA[PD(q+1536)] = csub(t1,t3i);
    }
  }
  __syncthreads();
}

// radix-4 DFT, +i convention
__device__ __forceinline__ void dft4p(float2 a[4]){
  float2 t0=cadd(a[0],a[2]), t1=csub(a[0],a[2]), t2=cadd(a[1],a[3]), t3=csub(a[1],a[3]);
  float2 t3i = make_float2(-t3.y, t3.x);
  a[0]=cadd(t0,t2); a[2]=csub(t0,t2);
  a[1]=cadd(t1,t3i); a[3]=csub(t1,t3i);
}

// One block per (b,d). Thread owns lo bins {4t..4t+3}; hi bins are conj mirrors.
template<bool TRANSP>
__global__ __launch_bounds__(256, 1) void vmd_main(const float* __restrict__ xg,
                                                   float* __restrict__ uout,
                                                   float* __restrict__ omout)
{
  __shared__ float2 sbufA[2112];   // init FFT A; then TY[w*264 + 66r + m]
  __shared__ float2 sbufB[2112];   // init FFT B; then staged lo spectrum slot(q)=(q&3)*528+(q>>2)
  __shared__ float2 stwd[1024];    // e^{2*pi*i*j/2048}
  __shared__ float4 sred4[6];      // omega partials [k][w]

  float2* sS  = sbufB;
  float2* sTY = sbufA;
  float*  sredf = (float*)sred4;

  const int t = threadIdx.x;
  const int lane = t & 63;
  const int w = t >> 6;
  const int blk = blockIdx.x;
  const int b = blk >> 5;
  const int d = blk & 31;
  const float inv2048 = 1.0f/2048.0f;

  for (int j = t; j < 1024; j += 256) {
    double th = 3.14159265358979323846 * (double)j / 1024.0;
    stwd[j] = make_float2((float)cos(th), (float)sin(th));
  }

  int idxs[8];
  float fl[4];
  #pragma unroll
  for (int c = 0; c < 4; c++) {
    int iL = 4*t + c;
    idxs[c]   = iL;
    idxs[c+4] = (iL == 0) ? 1024 : (2048 - iL);
    fl[c] = (float)(iL - 1024) * inv2048;
  }

  float xv[8];
  #pragma unroll
  for (int e = 0; e < 8; e++) xv[e] = xg[(b*2048 + idxs[e])*32 + d];

  // ---- init: X_shift = FFT(x * (-1)^n) ----
  #pragma unroll
  for (int e = 0; e < 8; e++) {
    float v = (idxs[e] & 1) ? -xv[e] : xv[e];
    sbufA[PD(idxs[e])] = make_float2(v, 0.0f);
  }
  __syncthreads();
  fft2048<-1>(sbufA, sbufB, stwd, t);
  float2 X[4];
  if (t == 0) X[0] = make_float2(sbufA[PD(0)].x, sbufA[PD(1024)].x);  // (bin0, bin1024) reals
  else        X[0] = sbufA[PD(4*t)];
  X[1] = sbufA[PD(4*t+1)];
  X[2] = sbufA[PD(4*t+2)];
  X[3] = sbufA[PD(4*t+3)];
  // fft2048 ends with a barrier; first reuse writes are ordered by B1 below.

  // ---- hoisted invariants ----
  int r6 = ((lane&1)<<5)|((lane&2)<<3)|((lane&4)<<1)|((lane&8)>>1)|((lane&16)>>3)|((lane&32)>>5);
  const int prb = w*528 + lane;               // lo pack read base; +64j
  int hA[4];                                  // conj-mirror pack read addrs
  #pragma unroll
  for (int j=0;j<4;j++)
    hA[j] = (w==0) ? (256 - 64*j - lane) : ((4-w)*528 + 255 - 64*j - lane);
  float2 wq[4];
  #pragma unroll
  for (int j=0;j<4;j++) wq[j] = stwd[4*lane + 256*j + w];   // W2048^{q_j}
  float2 w2561 = stwd[8*lane];                // W256^lane
  float2 w2562 = stwd[16*lane & 2047];
  float2 w2563 = cmul(w2561, w2562);
  const float sg32 = (lane&32)?-1.f:1.f, sg16 = (lane&16)?-1.f:1.f, sg8 = (lane&8)?-1.f:1.f;
  const float sg4  = (lane&4) ?-1.f:1.f, sg2  = (lane&2) ?-1.f:1.f, sg1 = (lane&1)?-1.f:1.f;
  const float2 one = make_float2(1.f, 0.f);
  float2 tw32 = (lane&32)? stwd[32*(lane&31)]  : one;
  float2 tw16 = (lane&16)? stwd[64*(lane&15)]  : one;
  float2 tw8  = (lane&8) ? stwd[128*(lane&7)]  : one;
  float2 tw4  = (lane&4) ? stwd[256*(lane&3)]  : one;
  float2 tw2  = (lane&2) ? stwd[512*(lane&1)]  : one;
  const int bp32 = ((lane^32) << 2);
  const int tyb = w*264 + r6;                 // TY write base; +66r
  float2 tytw[4];
  #pragma unroll
  for (int r=0;r<4;r++){
    int xx2 = 2*w*(r + 4*r6);                 // <= 1530
    tytw[r] = (xx2 < 1024) ? stwd[xx2]
            : make_float2(-stwd[xx2-1024].x, -stwd[xx2-1024].y);
  }
  // z-read slots + combine weights: z[k] = (TY0+s2*TY2) + phi*(TY1+s2*TY3), phi=i^{k1}
  int slA, slB, slC, slD, slE;
  float2 phA, phB, phC, phD, phE;
  float s2A, s2B, s2C, s2D, s2E;
  {
    int ks[5];
    ks[0] = 2*t; ks[1] = 2*t+1;
    ks[2] = (t==0) ? 512 : (1024 - 2*t);
    ks[3] = 1023 - 2*t; ks[4] = 1022 - 2*t;
    int   sl[5]; float2 ph[5]; float s2[5];
    #pragma unroll
    for (int i=0;i<5;i++){
      int k1 = ks[i] >> 8, k2 = ks[i] & 255;
      sl[i] = 66*(k2 & 3) + (k2 >> 2);
      float2 P = (k1==0)? make_float2(1,0) : (k1==1)? make_float2(0,1)
               : (k1==2)? make_float2(-1,0) : make_float2(0,-1);
      ph[i] = P; s2[i] = (k1 & 1) ? -1.f : 1.f;
    }
    slA=sl[0]; slB=sl[1]; slC=sl[2]; slD=sl[3]; slE=sl[4];
    phA=ph[0]; phB=ph[1]; phC=ph[2]; phD=ph[3]; phE=ph[4];
    s2A=s2[0]; s2B=s2[1]; s2C=s2[2]; s2D=s2[3]; s2E=s2[4];
  }

  // stage lo-half spectrum only (mirrors reconstructed at pack time)
  auto stageSpec = [&](float2 v0, float2 v1, float2 v2, float2 v3){
    if (t == 0) { sS[0] = make_float2(v0.x, 0.f); sS[256] = make_float2(v0.y, 0.f); }
    else          sS[t] = v0;
    sS[528  + t] = v1;
    sS[1056 + t] = v2;
    sS[1584 + t] = v3;
  };

  // pack + 1024-pt DFT+ (per-wave residue class) -> sTY. Caller: barrier before & after.
  auto runFFT = [&](){
    float2 C[4];
    #pragma unroll
    for (int j=0;j<4;j++){
      float2 lo = sS[prb + 64*j];
      float2 h  = sS[hA[j]];                 // conj(B[q+1024]) source
      float2 Av = make_float2(lo.x + h.x, lo.y - h.y);
      float2 Bv = make_float2(lo.x - h.x, lo.y + h.y);
      float2 WB = cmul(wq[j], Bv);
      C[j] = make_float2(Av.x - WB.y, Av.y + WB.x);   // Av + i*W*Bv
    }
    dft4p(C);                                          // in-register radix-4 over j
    C[1] = cmul(C[1], w2561); C[2] = cmul(C[2], w2562); C[3] = cmul(C[3], w2563);
    #pragma unroll
    for (int r=0;r<4;r++){                             // s=32 (ds_bpermute)
      float2 e = exbp(bp32, C[r]);
      C[r] = cmul(make_float2(fmaf(sg32, C[r].x, e.x), fmaf(sg32, C[r].y, e.y)), tw32);
    }
    #pragma unroll
    for (int r=0;r<4;r++){                             // s=16 (ds_swizzle xor16)
      float2 e = exswz<0x401F>(C[r]);
      C[r] = cmul(make_float2(fmaf(sg16, C[r].x, e.x), fmaf(sg16, C[r].y, e.y)), tw16);
    }
    #pragma unroll
    for (int r=0;r<4;r++){                             // s=8 (DPP row_ror:8 = xor8)
      float2 e = exdpp<0x128>(C[r]);
      C[r] = cmul(make_float2(fmaf(sg8, C[r].x, e.x), fmaf(sg8, C[r].y, e.y)), tw8);
    }
    #pragma unroll
    for (int r=0;r<4;r++){                             // s=4 (ds_swizzle)
      float2 e = exswz<0x101F>(C[r]);
      C[r] = cmul(make_float2(fmaf(sg4, C[r].x, e.x), fmaf(sg4, C[r].y, e.y)), tw4);
    }
    #pragma unroll
    for (int r=0;r<4;r++){                             // s=2 (DPP)
      float2 e = exdpp<0x4E>(C[r]);
      C[r] = cmul(make_float2(fmaf(sg2, C[r].x, e.x), fmaf(sg2, C[r].y, e.y)), tw2);
    }
    #pragma unroll
    for (int r=0;r<4;r++){                             // s=1 (DPP, no twiddle)
      float2 e = exdpp<0xB1>(C[r]);
      C[r] = make_float2(fmaf(sg1, C[r].x, e.x), fmaf(sg1, C[r].y, e.y));
    }
    #pragma unroll
    for (int r=0;r<4;r++) sTY[tyb + 66*r] = cmul(C[r], tytw[r]);
  };

  auto zread = [&](int sl, float2 phi, float s2) -> float2 {
    float2 a0 = sTY[sl], a1 = sTY[sl+264], a2 = sTY[sl+528], a3 = sTY[sl+792];
    float ex = fmaf(s2, a2.x, a0.x), ey = fmaf(s2, a2.y, a0.y);
    float ox = fmaf(s2, a3.x, a1.x), oy = fmaf(s2, a3.y, a1.y);
    return make_float2(ex + phi.x*ox - phi.y*oy, ey + phi.x*oy + phi.y*ox);
  };

  // ---- state (lo half only; t==0 slot c=0 packs the two real self-bins) ----
  float2 U[3][4], S[4];
  float lam2[8];
  #pragma unroll
  for (int c=0;c<4;c++){ S[c] = make_float2(0.f,0.f);
    #pragma unroll
    for (int k=0;k<3;k++) U[k][c] = make_float2(0.f,0.f); }
  #pragma unroll
  for (int e=0;e<8;e++) lam2[e] = 0.f;
  float om[3] = {0.f,0.f,0.f};

  for (int iter = 0; iter < 100; ++iter) {
    float sf[3], sp[3];
    #pragma unroll
    for (int k = 0; k < 3; k++) {
      float omk = om[k];
      sf[k] = 0.f; sp[k] = 0.f;
      // c = 0
      if (t == 0) {
        float2 Uo = U[k][0];
        float n0 = X[0].x + lam2[0] - S[0].x + Uo.x;   // bin 0 (f=-1/2)
        float n1 = X[0].y + lam2[4] - S[0].y + Uo.y;   // bin 1024 (f=0)
        float d0 = -0.5f - omk, d1 = -omk;
        float u0 = n0 * __builtin_amdgcn_rcpf(fmaf(4000.f*d0, d0, 1.f));
        float u1 = n1 * __builtin_amdgcn_rcpf(fmaf(4000.f*d1, d1, 1.f));
        sp[k] += u1*u1;
        S[0].x += u0 - Uo.x; S[0].y += u1 - Uo.y;
        U[k][0] = make_float2(u0, u1);
      } else {
        float2 Uo = U[k][0];
        float bx = X[0].x - S[0].x + Uo.x;
        float by = X[0].y - S[0].y + Uo.y;
        float nl = bx + lam2[0], nh = bx + lam2[4];
        float dl = fl[0] - omk, dh = -fl[0] - omk;
        float rl = __builtin_amdgcn_rcpf(fmaf(4000.f*dl, dl, 1.f));
        float rh = __builtin_amdgcn_rcpf(fmaf(4000.f*dh, dh, 1.f));
        float ux = 0.5f*fmaf(nl, rl, nh*rh);
        float uy = 0.5f*by*(rl+rh);
        S[0].x += ux - Uo.x; S[0].y += uy - Uo.y;
        U[k][0] = make_float2(ux, uy);
        float pw = fmaf(ux, ux, uy*uy);
        sf[k] = fmaf(-fl[0], pw, sf[k]); sp[k] += pw;
      }
      #pragma unroll
      for (int c = 1; c < 4; c++) {
        float2 Uo = U[k][c];
        float bx = X[c].x - S[c].x + Uo.x;
        float by = X[c].y - S[c].y + Uo.y;
        float nl = bx + lam2[c], nh = bx + lam2[4+c];
        float dl = fl[c] - omk, dh = -fl[c] - omk;
        float rl = __builtin_amdgcn_rcpf(fmaf(4000.f*dl, dl, 1.f));
        float rh = __builtin_amdgcn_rcpf(fmaf(4000.f*dh, dh, 1.f));
        float ux = 0.5f*fmaf(nl, rl, nh*rh);
        float uy = 0.5f*by*(rl+rh);
        S[c].x += ux - Uo.x; S[c].y += uy - Uo.y;
        U[k][c] = make_float2(ux, uy);
        float pw = fmaf(ux, ux, uy*uy);
        sf[k] = fmaf(-fl[c], pw, sf[k]); sp[k] += pw;
      }
    }

    stageSpec(S[0], S[1], S[2], S[3]);

    #pragma unroll
    for (int k = 0; k < 3; k++) { sf[k] = wave_sum64(sf[k]); sp[k] = wave_sum64(sp[k]); }
    if (lane == 63) {
      #pragma unroll
      for (int k = 0; k < 3; k++) { sredf[k*4 + w] = sf[k]; sredf[(3+k)*4 + w] = sp[k]; }
    }
    __syncthreads();   // B1: staged S + sred + (prev-iter TY reads)

    runFFT();

    // omega readback (sunk after FFT issue; must stay before B2)
    #pragma unroll
    for (int k = 0; k < 3; k++) {
      float4 A = sred4[k];
      float4 P = sred4[3+k];
      float a = (A.x + A.y) + (A.z + A.w);
      float p = (P.x + P.y) + (P.z + P.w);
      om[k] = a * __builtin_amdgcn_rcpf(p + 1e-7f);
    }
    __syncthreads();   // B2: TY visible

    {
      float2 zA = zread(slA, phA, s2A);
      float2 zB = zread(slB, phB, s2B);
      float2 zC = zread(slC, phC, s2C);
      float2 zD = zread(slD, phD, s2D);
      float2 zE = zread(slE, phE, s2E);
      lam2[0] = fmaf(0.0005f, xv[0] - zA.x*inv2048, lam2[0]);
      lam2[1] = fmaf(0.0005f, xv[1] + zA.y*inv2048, lam2[1]);
      lam2[2] = fmaf(0.0005f, xv[2] - zB.x*inv2048, lam2[2]);
      lam2[3] = fmaf(0.0005f, xv[3] + zB.y*inv2048, lam2[3]);
      lam2[4] = fmaf(0.0005f, xv[4] - zC.x*inv2048, lam2[4]);
      lam2[5] = fmaf(0.0005f, xv[5] + zD.y*inv2048, lam2[5]);
      lam2[6] = fmaf(0.0005f, xv[6] - zD.x*inv2048, lam2[6]);
      lam2[7] = fmaf(0.0005f, xv[7] + zE.y*inv2048, lam2[7]);
    }
    // no trailing barrier: next iter's B1 orders TY reads vs next writes
  }

  // ---- final: u_k(time) ----
  #pragma unroll
  for (int k = 0; k < 3; k++) {
    stageSpec(U[k][0], U[k][1], U[k][2], U[k][3]);
    __syncthreads();
    runFFT();
    __syncthreads();
    {
      float2 zA = zread(slA, phA, s2A);
      float2 zB = zread(slB, phB, s2B);
      float2 zC = zread(slC, phC, s2C);
      float2 zD = zread(slD, phD, s2D);
      float2 zE = zread(slE, phE, s2E);
      float g[8];
      g[0] =  zA.x; g[1] = -zA.y; g[2] =  zB.x; g[3] = -zB.y;
      g[4] =  zC.x; g[5] = -zD.y; g[6] =  zD.x; g[7] = -zE.y;
      #pragma unroll
      for (int e = 0; e < 8; e++) {
        float uv = g[e] * inv2048;
        if (TRANSP) uout[(((size_t)k*8 + b)*32 + d)*2048 + idxs[e]] = uv;   // ws: [k][b][d][l]
        else        uout[(size_t)k*BLD + ((size_t)b*2048 + idxs[e])*32 + d] = uv;
      }
    }
  }
  if (t == 0) {
    omout[(b*3 + 0)*32 + d] = om[0];
    omout[(b*3 + 1)*32 + d] = om[1];
    omout[(b*3 + 2)*32 + d] = om[2];
  }
}

__device__ __forceinline__ void order3(const float* sm, int* sord){
  float v0=sm[0], v1=sm[1], v2=sm[2];
  int j0=0,j1=1,j2=2;
  if (v1<v0){float tv=v0;v0=v1;v1=tv;int ti=j0;j0=j1;j1=ti;}
  if (v2<v1){float tv=v1;v1=v2;v2=tv;int ti=j1;j1=j2;j2=ti;}
  if (v1<v0){float tv=v0;v0=v1;v1=tv;int ti=j0;j0=j1;j1=ti;}
  sord[0]=j0; sord[1]=j1; sord[2]=j2;
}

// ws[ord[k]][b][d][l] -> out[k][b][l][d]
__global__ __launch_bounds__(256) void vmd_permute(const float* __restrict__ wsu,
                                                   const float* __restrict__ omout,
                                                   float* __restrict__ out)
{
  __shared__ float tile[32][33];
  __shared__ float sm[3];
  __shared__ int sord[3];
  int bid = blockIdx.x;
  int lt = bid & 63;
  int b = (bid >> 6) & 7;
  int kpos = bid >> 9;
  int tid = threadIdx.x;
  if (tid < 3) {
    float s = 0.f;
    for (int dd = 0; dd < 32; dd++) s += omout[(b*3 + tid)*32 + dd];
    sm[tid] = s;
  }
  __syncthreads();
  if (tid == 0) order3(sm, sord);
  __syncthreads();
  int ks = sord[kpos];
  int tr = tid >> 5, tc = tid & 31;
  for (int it = 0; it < 4; it++) {
    int dd = tr + it*8;
    tile[dd][tc] = wsu[(((size_t)ks*8 + b)*32 + dd)*2048 + lt*32 + tc];
  }
  __syncthreads();
  for (int it = 0; it < 4; it++) {
    int ll = tr + it*8;
    out[(size_t)kpos*BLD + ((size_t)b*2048 + lt*32 + ll)*32 + tc] = tile[tc][ll];
  }
}

// fallback: in-place k-plane permutation of d_out
__global__ void vmd_inplace(float* __restrict__ out, const float* __restrict__ omout)
{
  __shared__ float sm[3];
  __shared__ int sord[3];
  int r = blockIdx.x * 256 + threadIdx.x;   // < 524288; one b per block
  int b = r >> 16;
  if (threadIdx.x < 3) {
    float s = 0.f;
    for (int dd = 0; dd < 32; dd++) s += omout[(b*3 + threadIdx.x)*32 + dd];
    sm[threadIdx.x] = s;
  }
  __syncthreads();
  if (threadIdx.x == 0) order3(sm, sord);
  __syncthreads();
  int o0 = sord[0], o1 = sord[1], o2 = sord[2];
  float v0 = out[(size_t)o0*BLD + r];
  float v1 = out[(size_t)o1*BLD + r];
  float v2 = out[(size_t)o2*BLD + r];
  out[r] = v0;
  out[(size_t)BLD + r] = v1;
  out[(size_t)2*BLD + r] = v2;
}

extern "C" void kernel_launch(void* const* d_in, const int* in_sizes, int n_in,
                              void* d_out, int out_size, void* d_ws, size_t ws_size,
                              hipStream_t stream)
{
  const float* x = (const float*)d_in[0];
  float* out = (float*)d_out;
  const size_t NU = (size_t)3 * BLD;
  size_t need = NU*4 + 768*4;
  if (ws_size >= need) {
    float* wsu  = (float*)d_ws;
    float* wsom = wsu + NU;
    vmd_main<true><<<256, 256, 0, stream>>>(x, wsu, wsom);
    vmd_permute<<<1536, 256, 0, stream>>>(wsu, wsom, out);
  } else {
    float* wsom = (float*)d_ws;
    vmd_main<false><<<256, 256, 0, stream>>>(x, out, wsom);
    vmd_inplace<<<2048, 256, 0, stream>>>(out, wsom);
  }
}

// Round 10
// 296.055 us; speedup vs baseline: 1.0324x; 1.0324x over previous
//
#include <hip/hip_runtime.h>

#define PD(i) ((i) + ((i) >> 5))   // LDS pad (init FFT only)
#define BLD 524288                 // 8*2048*32

__device__ __forceinline__ float2 cadd(float2 a, float2 b){ return make_float2(a.x+b.x, a.y+b.y); }
__device__ __forceinline__ float2 csub(float2 a, float2 b){ return make_float2(a.x-b.x, a.y-b.y); }
__device__ __forceinline__ float2 cmul(float2 a, float2 b){ return make_float2(a.x*b.x - a.y*b.y, a.x*b.y + a.y*b.x); }
__device__ __forceinline__ float2 cmuli(float2 a, float s){ return make_float2(-s*a.y, s*a.x); }

// DPP wave64 sum; lane 63 holds the total.
template<int CTRL, int RM>
__device__ __forceinline__ float dpp_add(float x){
  int r = __builtin_amdgcn_update_dpp(0, __float_as_int(x), CTRL, RM, 0xf, true);
  return x + __int_as_float(r);
}
__device__ __forceinline__ float wave_sum64(float x){
  x = dpp_add<0x111,0xf>(x);
  x = dpp_add<0x112,0xf>(x);
  x = dpp_add<0x114,0xf>(x);
  x = dpp_add<0x118,0xf>(x);
  x = dpp_add<0x142,0xa>(x);
  x = dpp_add<0x143,0xc>(x);
  return x;
}

// cross-lane exchange helpers (wave64)
__device__ __forceinline__ float2 exbp(int addr, float2 v){
  return make_float2(
    __int_as_float(__builtin_amdgcn_ds_bpermute(addr, __float_as_int(v.x))),
    __int_as_float(__builtin_amdgcn_ds_bpermute(addr, __float_as_int(v.y))));
}
template<int PAT>
__device__ __forceinline__ float2 exswz(float2 v){
  return make_float2(
    __int_as_float(__builtin_amdgcn_ds_swizzle(__float_as_int(v.x), PAT)),
    __int_as_float(__builtin_amdgcn_ds_swizzle(__float_as_int(v.y), PAT)));
}
template<int CTRL>
__device__ __forceinline__ float2 exdpp(float2 v){
  return make_float2(
    __int_as_float(__builtin_amdgcn_update_dpp(0, __float_as_int(v.x), CTRL, 0xF, 0xF, true)),
    __int_as_float(__builtin_amdgcn_update_dpp(0, __float_as_int(v.y), CTRL, 0xF, 0xF, true)));
}

// DFT-8 (init FFT only)
template<int SGN>
__device__ __forceinline__ void dft8(float2 a[8]) {
  const float sgn = (float)SGN;
  const float C8 = 0.70710678118654752440f;
  float2 e0=a[0], e1=a[2], e2=a[4], e3=a[6];
  float2 o0=a[1], o1=a[3], o2=a[5], o3=a[7];
  float2 t0=cadd(e0,e2), t1=csub(e0,e2), t2=cadd(e1,e3), t3=csub(e1,e3);
  float2 E0=cadd(t0,t2), E2=csub(t0,t2);
  float2 t3i=cmuli(t3,sgn);
  float2 E1=cadd(t1,t3i), E3=csub(t1,t3i);
  float2 s0=cadd(o0,o2), s1=csub(o0,o2), s2=cadd(o1,o3), s3=csub(o1,o3);
  float2 O0=cadd(s0,s2), O2=csub(s0,s2);
  float2 s3i=cmuli(s3,sgn);
  float2 O1=cadd(s1,s3i), O3=csub(s1,s3i);
  float2 w1o = make_float2(C8*(O1.x - sgn*O1.y), C8*(O1.y + sgn*O1.x));
  float2 w2o = cmuli(O2, sgn);
  float2 w3o = make_float2(-C8*(O3.x + sgn*O3.y), C8*(sgn*O3.x - O3.y));
  a[0]=cadd(E0,O0); a[4]=csub(E0,O0);
  a[1]=cadd(E1,w1o); a[5]=csub(E1,w1o);
  a[2]=cadd(E2,w2o); a[6]=csub(E2,w2o);
  a[3]=cadd(E3,w3o); a[7]=csub(E3,w3o);
}

// Init-only 2048-pt Stockham FFT (radix 8,8,8,4), natural order, result in bufA.
template<int SGN>
__device__ void fft2048(float2* bufA, float2* bufB, const float2* twd, int tid)
{
  const float sgn = (float)SGN;
  {
    float2 a[8];
    #pragma unroll
    for (int j=0;j<8;j++) a[j] = bufA[PD(tid + 256*j)];
    dft8<SGN>(a);
    float2 tw = twd[tid];
    float2 w1 = make_float2(tw.x, sgn*tw.y), wj = w1;
    #pragma unroll
    for (int j=1;j<8;j++){ a[j] = cmul(a[j], wj); wj = cmul(wj, w1); }
    #pragma unroll
    for (int j=0;j<8;j++) bufB[PD(8*tid + j)] = a[j];
  }
  __syncthreads();
  {
    float2 a[8];
    #pragma unroll
    for (int j=0;j<8;j++) a[j] = bufB[PD(tid + 256*j)];
    dft8<SGN>(a);
    int p = tid >> 3, q = tid & 7;
    float2 tw = twd[p << 3];
    float2 w1 = make_float2(tw.x, sgn*tw.y), wj = w1;
    #pragma unroll
    for (int j=1;j<8;j++){ a[j] = cmul(a[j], wj); wj = cmul(wj, w1); }
    int base = q + (p << 6);
    #pragma unroll
    for (int j=0;j<8;j++) bufA[PD(base + (j<<3))] = a[j];
  }
  __syncthreads();
  {
    float2 a[8];
    #pragma unroll
    for (int j=0;j<8;j++) a[j] = bufA[PD(tid + 256*j)];
    dft8<SGN>(a);
    int p = tid >> 6, q = tid & 63;
    float2 tw = twd[p << 6];
    float2 w1 = make_float2(tw.x, sgn*tw.y), wj = w1;
    #pragma unroll
    for (int j=1;j<8;j++){ a[j] = cmul(a[j], wj); wj = cmul(wj, w1); }
    int base = q + (p << 9);
    #pragma unroll
    for (int j=0;j<8;j++) bufB[PD(base + (j<<6))] = a[j];
  }
  __syncthreads();
  {
    #pragma unroll
    for (int h=0; h<2; h++){
      int q = tid + (h<<8);
      float2 b0 = bufB[PD(q)], b1 = bufB[PD(q+512)], b2 = bufB[PD(q+1024)], b3 = bufB[PD(q+1536)];
      float2 t0=cadd(b0,b2), t1=csub(b0,b2), t2=cadd(b1,b3), t3=csub(b1,b3);
      float2 t3i=cmuli(t3,sgn);
      bufA[PD(q)]      = cadd(t0,t2);
      bufA[PD(q+512)]  = cadd(t1,t3i);
      bufA[PD(q+1024)] = csub(t0,t2);
      bufA[PD(q+1536)] = csub(t1,t3i);
    }
  }
  __syncthreads();
}

// radix-4 DFT, +i convention: out_r = sum_j a_j * i^{j r}
__device__ __forceinline__ void dft4p(float2 a[4]){
  float2 t0=cadd(a[0],a[2]), t1=csub(a[0],a[2]), t2=cadd(a[1],a[3]), t3=csub(a[1],a[3]);
  float2 t3i = make_float2(-t3.y, t3.x);
  a[0]=cadd(t0,t2); a[2]=csub(t0,t2);
  a[1]=cadd(t1,t3i); a[3]=csub(t1,t3i);
}

// One block per (b,d). Thread owns lo bins {4t..4t+3}; hi bins are conj mirrors.
template<bool TRANSP>
__global__ __launch_bounds__(256, 1) void vmd_main(const float* __restrict__ xg,
                                                   float* __restrict__ uout,
                                                   float* __restrict__ omout)
{
  __shared__ float2 sbufA[2112];   // init FFT A; then TY[w*264 + 66r + m]
  __shared__ float2 sbufB[2112];   // init FFT B; then staged spectrum slot(q)=(q&3)*528+(q>>2)
  __shared__ float2 stwd[1024];    // e^{2*pi*i*j/2048}
  __shared__ float  sred[24];

  float2* sS  = sbufB;
  float2* sTY = sbufA;

  const int t = threadIdx.x;
  const int lane = t & 63;
  const int w = t >> 6;
  const int blk = blockIdx.x;
  const int b = blk >> 5;
  const int d = blk & 31;
  const float inv2048 = 1.0f/2048.0f;

  for (int j = t; j < 1024; j += 256) {
    double th = 3.14159265358979323846 * (double)j / 1024.0;
    stwd[j] = make_float2((float)cos(th), (float)sin(th));
  }

  int idxs[8];
  float fl[4];
  #pragma unroll
  for (int c = 0; c < 4; c++) {
    int iL = 4*t + c;
    idxs[c]   = iL;
    idxs[c+4] = (iL == 0) ? 1024 : (2048 - iL);
    fl[c] = (float)(iL - 1024) * inv2048;
  }

  float xv[8];
  #pragma unroll
  for (int e = 0; e < 8; e++) xv[e] = xg[(b*2048 + idxs[e])*32 + d];

  // ---- init: X_shift = FFT(x * (-1)^n) ----
  #pragma unroll
  for (int e = 0; e < 8; e++) {
    float v = (idxs[e] & 1) ? -xv[e] : xv[e];
    sbufA[PD(idxs[e])] = make_float2(v, 0.0f);
  }
  __syncthreads();
  fft2048<-1>(sbufA, sbufB, stwd, t);
  float2 X[4];
  if (t == 0) X[0] = make_float2(sbufA[PD(0)].x, sbufA[PD(1024)].x);  // (bin0, bin1024) reals
  else        X[0] = sbufA[PD(4*t)];
  X[1] = sbufA[PD(4*t+1)];
  X[2] = sbufA[PD(4*t+2)];
  X[3] = sbufA[PD(4*t+3)];
  // fft2048 ends with a barrier; stale sbufA/sbufB are dead; first reuse writes
  // (staging->sS, TY->sTY) are ordered by B1 below.

  // ---- hoisted invariants ----
  int r6 = ((lane&1)<<5)|((lane&2)<<3)|((lane&4)<<1)|((lane&8)>>1)|((lane&16)>>3)|((lane&32)>>5);
  const int prb = w*528 + lane;               // pack read base; +64j, +256 for hi
  float2 wq[4];
  #pragma unroll
  for (int j=0;j<4;j++) wq[j] = stwd[4*lane + 256*j + w];   // W2048^{q_j}
  float2 w2561 = stwd[8*lane];                // W256^lane
  float2 w2562 = stwd[16*lane & 2047];
  float2 w2563 = cmul(w2561, w2562);
  const float sg32 = (lane&32)?-1.f:1.f, sg16 = (lane&16)?-1.f:1.f, sg8 = (lane&8)?-1.f:1.f;
  const float sg4  = (lane&4) ?-1.f:1.f, sg2  = (lane&2) ?-1.f:1.f, sg1 = (lane&1)?-1.f:1.f;
  const bool  bI   = ((lane & 3) == 3);       // s=2 stage: tw2 = i exactly on these lanes, else 1
  const float2 one = make_float2(1.f, 0.f);
  float2 tw32 = (lane&32)? stwd[32*(lane&31)]  : one;
  float2 tw16 = (lane&16)? stwd[64*(lane&15)]  : one;
  float2 tw8  = (lane&8) ? stwd[128*(lane&7)]  : one;
  float2 tw4  = (lane&4) ? stwd[256*(lane&3)]  : one;
  const int bp32 = ((lane^32) << 2);
  const int tyb = w*264 + r6;                 // TY write base; +66r
  float2 tytw[4];
  #pragma unroll
  for (int r=0;r<4;r++){
    int xx2 = 2*w*(r + 4*r6);                 // <= 1530
    tytw[r] = (xx2 < 1024) ? stwd[xx2]
            : make_float2(-stwd[xx2-1024].x, -stwd[xx2-1024].y);
  }
  // z-read slots + combine weights: z[k] = (TY0+s2*TY2) + phi*(TY1+s2*TY3), phi=i^{k1}
  int slA, slB, slC, slD, slE;
  float2 phA, phB, phC, phD, phE;
  float s2A, s2B, s2C, s2D, s2E;
  {
    int ks[5];
    ks[0] = 2*t; ks[1] = 2*t+1;
    ks[2] = (t==0) ? 512 : (1024 - 2*t);
    ks[3] = 1023 - 2*t; ks[4] = 1022 - 2*t;
    int   sl[5]; float2 ph[5]; float s2[5];
    #pragma unroll
    for (int i=0;i<5;i++){
      int k1 = ks[i] >> 8, k2 = ks[i] & 255;
      sl[i] = 66*(k2 & 3) + (k2 >> 2);
      float2 P = (k1==0)? make_float2(1,0) : (k1==1)? make_float2(0,1)
               : (k1==2)? make_float2(-1,0) : make_float2(0,-1);
      ph[i] = P; s2[i] = (k1 & 1) ? -1.f : 1.f;
    }
    slA=sl[0]; slB=sl[1]; slC=sl[2]; slD=sl[3]; slE=sl[4];
    phA=ph[0]; phB=ph[1]; phC=ph[2]; phD=ph[3]; phE=ph[4];
    s2A=s2[0]; s2B=s2[1]; s2C=s2[2]; s2D=s2[3]; s2E=s2[4];
  }

  // stage Hermitian spectrum (lo values per thread) into sS slot layout
  auto stageSpec = [&](float2 v0, float2 v1, float2 v2, float2 v3){
    if (t == 0) { sS[0] = make_float2(v0.x, 0.f); sS[256] = make_float2(v0.y, 0.f); }
    else        { sS[t] = v0;                     sS[512 - t] = make_float2(v0.x, -v0.y); }
    sS[528  + t] = v1;  sS[2095 - t] = make_float2(v1.x, -v1.y);
    sS[1056 + t] = v2;  sS[1567 - t] = make_float2(v2.x, -v2.y);
    sS[1584 + t] = v3;  sS[1039 - t] = make_float2(v3.x, -v3.y);
  };

  // pack + 1024-pt DFT+ (per-wave residue class) -> sTY. Caller: barrier before & after.
  auto runFFT = [&](){
    float2 C[4];
    #pragma unroll
    for (int j=0;j<4;j++){
      float2 lo = sS[prb + 64*j];
      float2 hi = sS[prb + 64*j + 256];
      float2 Av = cadd(lo, hi), Bv = csub(lo, hi);
      float2 WB = cmul(wq[j], Bv);
      C[j] = make_float2(Av.x - WB.y, Av.y + WB.x);   // Av + i*W*Bv
    }
    dft4p(C);                                          // in-register radix-4 over j
    C[1] = cmul(C[1], w2561); C[2] = cmul(C[2], w2562); C[3] = cmul(C[3], w2563);
    #pragma unroll
    for (int r=0;r<4;r++){                             // s=32 (bpermute)
      float2 e = exbp(bp32, C[r]);
      C[r] = cmul(make_float2(fmaf(sg32, C[r].x, e.x), fmaf(sg32, C[r].y, e.y)), tw32);
    }
    #pragma unroll
    for (int r=0;r<4;r++){                             // s=16 (ds_swizzle xor16)
      float2 e = exswz<0x401F>(C[r]);
      C[r] = cmul(make_float2(fmaf(sg16, C[r].x, e.x), fmaf(sg16, C[r].y, e.y)), tw16);
    }
    #pragma unroll
    for (int r=0;r<4;r++){                             // s=8 (DPP row_ror:8 = xor8)
      float2 e = exdpp<0x128>(C[r]);
      C[r] = cmul(make_float2(fmaf(sg8, C[r].x, e.x), fmaf(sg8, C[r].y, e.y)), tw8);
    }
    #pragma unroll
    for (int r=0;r<4;r++){                             // s=4 (ds_swizzle)
      float2 e = exswz<0x101F>(C[r]);
      C[r] = cmul(make_float2(fmaf(sg4, C[r].x, e.x), fmaf(sg4, C[r].y, e.y)), tw4);
    }
    #pragma unroll
    for (int r=0;r<4;r++){                             // s=2 (DPP; tw2 is exactly 1 or i)
      float2 e = exdpp<0x4E>(C[r]);
      float sx = fmaf(sg2, C[r].x, e.x);
      float sy = fmaf(sg2, C[r].y, e.y);
      C[r] = bI ? make_float2(-sy, sx) : make_float2(sx, sy);
    }
    #pragma unroll
    for (int r=0;r<4;r++){                             // s=1 (DPP, no twiddle)
      float2 e = exdpp<0xB1>(C[r]);
      C[r] = make_float2(fmaf(sg1, C[r].x, e.x), fmaf(sg1, C[r].y, e.y));
    }
    #pragma unroll
    for (int r=0;r<4;r++) sTY[tyb + 66*r] = cmul(C[r], tytw[r]);
  };

  auto zread = [&](int sl, float2 phi, float s2) -> float2 {
    float2 a0 = sTY[sl], a1 = sTY[sl+264], a2 = sTY[sl+528], a3 = sTY[sl+792];
    float ex = fmaf(s2, a2.x, a0.x), ey = fmaf(s2, a2.y, a0.y);
    float ox = fmaf(s2, a3.x, a1.x), oy = fmaf(s2, a3.y, a1.y);
    return make_float2(ex + phi.x*ox - phi.y*oy, ey + phi.x*oy + phi.y*ox);
  };

  // ---- state (lo half only; t==0 slot c=0 packs the two real self-bins) ----
  float2 U[3][4], S[4];
  float lam2[8];
  #pragma unroll
  for (int c=0;c<4;c++){ S[c] = make_float2(0.f,0.f);
    #pragma unroll
    for (int k=0;k<3;k++) U[k][c] = make_float2(0.f,0.f); }
  #pragma unroll
  for (int e=0;e<8;e++) lam2[e] = 0.f;
  float om[3] = {0.f,0.f,0.f};

  for (int iter = 0; iter < 100; ++iter) {
    float sf[3], sp[3];
    #pragma unroll
    for (int k = 0; k < 3; k++) {
      float omk = om[k];
      sf[k] = 0.f; sp[k] = 0.f;
      // c = 0
      if (t == 0) {
        float2 Uo = U[k][0];
        float n0 = X[0].x + lam2[0] - S[0].x + Uo.x;   // bin 0 (f=-1/2)
        float n1 = X[0].y + lam2[4] - S[0].y + Uo.y;   // bin 1024 (f=0)
        float d0 = -0.5f - omk, d1 = -omk;
        float u0 = n0 * __builtin_amdgcn_rcpf(fmaf(4000.f*d0, d0, 1.f));
        float u1 = n1 * __builtin_amdgcn_rcpf(fmaf(4000.f*d1, d1, 1.f));
        sp[k] += u1*u1;                                // f=0 counted, sf contrib 0
        S[0].x += u0 - Uo.x; S[0].y += u1 - Uo.y;
        U[k][0] = make_float2(u0, u1);
      } else {
        float2 Uo = U[k][0];
        float bx = X[0].x - S[0].x + Uo.x;
        float by = X[0].y - S[0].y + Uo.y;
        float nl = bx + lam2[0], nh = bx + lam2[4];
        float dl = fl[0] - omk, dh = -fl[0] - omk;
        float rl = __builtin_amdgcn_rcpf(fmaf(4000.f*dl, dl, 1.f));
        float rh = __builtin_amdgcn_rcpf(fmaf(4000.f*dh, dh, 1.f));
        float ux = 0.5f*fmaf(nl, rl, nh*rh);
        float uy = 0.5f*by*(rl+rh);
        S[0].x += ux - Uo.x; S[0].y += uy - Uo.y;
        U[k][0] = make_float2(ux, uy);
        float pw = fmaf(ux, ux, uy*uy);
        sf[k] = fmaf(-fl[0], pw, sf[k]); sp[k] += pw;
      }
      #pragma unroll
      for (int c = 1; c < 4; c++) {
        float2 Uo = U[k][c];
        float bx = X[c].x - S[c].x + Uo.x;
        float by = X[c].y - S[c].y + Uo.y;
        float nl = bx + lam2[c], nh = bx + lam2[4+c];
        float dl = fl[c] - omk, dh = -fl[c] - omk;
        float rl = __builtin_amdgcn_rcpf(fmaf(4000.f*dl, dl, 1.f));
        float rh = __builtin_amdgcn_rcpf(fmaf(4000.f*dh, dh, 1.f));
        float ux = 0.5f*fmaf(nl, rl, nh*rh);
        float uy = 0.5f*by*(rl+rh);
        S[c].x += ux - Uo.x; S[c].y += uy - Uo.y;
        U[k][c] = make_float2(ux, uy);
        float pw = fmaf(ux, ux, uy*uy);
        sf[k] = fmaf(-fl[c], pw, sf[k]); sp[k] += pw;
      }
    }

    stageSpec(S[0], S[1], S[2], S[3]);

    #pragma unroll
    for (int k = 0; k < 3; k++) { sf[k] = wave_sum64(sf[k]); sp[k] = wave_sum64(sp[k]); }
    if (lane == 63) {
      #pragma unroll
      for (int k = 0; k < 3; k++) { sred[w*6 + k] = sf[k]; sred[w*6 + 3 + k] = sp[k]; }
    }
    __syncthreads();   // B1: staged S + sred + (prev-iter TY reads)

    #pragma unroll
    for (int k = 0; k < 3; k++) {
      float a = sred[k] + sred[6+k] + sred[12+k] + sred[18+k];
      float p = sred[3+k] + sred[9+k] + sred[15+k] + sred[21+k];
      om[k] = a * __builtin_amdgcn_rcpf(p + 1e-7f);
    }

    runFFT();
    __syncthreads();   // B2: TY visible

    {
      float2 zA = zread(slA, phA, s2A);
      float2 zB = zread(slB, phB, s2B);
      float2 zC = zread(slC, phC, s2C);
      float2 zD = zread(slD, phD, s2D);
      float2 zE = zread(slE, phE, s2E);
      lam2[0] = fmaf(0.0005f, xv[0] - zA.x*inv2048, lam2[0]);
      lam2[1] = fmaf(0.0005f, xv[1] + zA.y*inv2048, lam2[1]);
      lam2[2] = fmaf(0.0005f, xv[2] - zB.x*inv2048, lam2[2]);
      lam2[3] = fmaf(0.0005f, xv[3] + zB.y*inv2048, lam2[3]);
      lam2[4] = fmaf(0.0005f, xv[4] - zC.x*inv2048, lam2[4]);
      lam2[5] = fmaf(0.0005f, xv[5] + zD.y*inv2048, lam2[5]);
      lam2[6] = fmaf(0.0005f, xv[6] - zD.x*inv2048, lam2[6]);
      lam2[7] = fmaf(0.0005f, xv[7] + zE.y*inv2048, lam2[7]);
    }
    // no trailing barrier: next iter's B1 orders TY reads vs next writes
  }

  // ---- final: u_k(time) ----
  #pragma unroll
  for (int k = 0; k < 3; k++) {
    stageSpec(U[k][0], U[k][1], U[k][2], U[k][3]);
    __syncthreads();
    runFFT();
    __syncthreads();
    {
      float2 zA = zread(slA, phA, s2A);
      float2 zB = zread(slB, phB, s2B);
      float2 zC = zread(slC, phC, s2C);
      float2 zD = zread(slD, phD, s2D);
      float2 zE = zread(slE, phE, s2E);
      float g[8];
      g[0] =  zA.x; g[1] = -zA.y; g[2] =  zB.x; g[3] = -zB.y;
      g[4] =  zC.x; g[5] = -zD.y; g[6] =  zD.x; g[7] = -zE.y;
      #pragma unroll
      for (int e = 0; e < 8; e++) {
        float uv = g[e] * inv2048;
        if (TRANSP) uout[(((size_t)k*8 + b)*32 + d)*2048 + idxs[e]] = uv;   // ws: [k][b][d][l]
        else        uout[(size_t)k*BLD + ((size_t)b*2048 + idxs[e])*32 + d] = uv;
      }
    }
  }
  if (t == 0) {
    omout[(b*3 + 0)*32 + d] = om[0];
    omout[(b*3 + 1)*32 + d] = om[1];
    omout[(b*3 + 2)*32 + d] = om[2];
  }
}

__device__ __forceinline__ void order3(const float* sm, int* sord){
  float v0=sm[0], v1=sm[1], v2=sm[2];
  int j0=0,j1=1,j2=2;
  if (v1<v0){float tv=v0;v0=v1;v1=tv;int ti=j0;j0=j1;j1=ti;}
  if (v2<v1){float tv=v1;v1=v2;v2=tv;int ti=j1;j1=j2;j2=ti;}
  if (v1<v0){float tv=v0;v0=v1;v1=tv;int ti=j0;j0=j1;j1=ti;}
  sord[0]=j0; sord[1]=j1; sord[2]=j2;
}

// ws[ord[k]][b][d][l] -> out[k][b][l][d]
__global__ __launch_bounds__(256) void vmd_permute(const float* __restrict__ wsu,
                                                   const float* __restrict__ omout,
                                                   float* __restrict__ out)
{
  __shared__ float tile[32][33];
  __shared__ float sm[3];
  __shared__ int sord[3];
  int bid = blockIdx.x;
  int lt = bid & 63;
  int b = (bid >> 6) & 7;
  int kpos = bid >> 9;
  int tid = threadIdx.x;
  if (tid < 3) {
    float s = 0.f;
    for (int dd = 0; dd < 32; dd++) s += omout[(b*3 + tid)*32 + dd];
    sm[tid] = s;
  }
  __syncthreads();
  if (tid == 0) order3(sm, sord);
  __syncthreads();
  int ks = sord[kpos];
  int tr = tid >> 5, tc = tid & 31;
  for (int it = 0; it < 4; it++) {
    int dd = tr + it*8;
    tile[dd][tc] = wsu[(((size_t)ks*8 + b)*32 + dd)*2048 + lt*32 + tc];
  }
  __syncthreads();
  for (int it = 0; it < 4; it++) {
    int ll = tr + it*8;
    out[(size_t)kpos*BLD + ((size_t)b*2048 + lt*32 + ll)*32 + tc] = tile[tc][ll];
  }
}

// fallback: in-place k-plane permutation of d_out
__global__ void vmd_inplace(float* __restrict__ out, const float* __restrict__ omout)
{
  __shared__ float sm[3];
  __shared__ int sord[3];
  int r = blockIdx.x * 256 + threadIdx.x;   // < 524288; one b per block
  int b = r >> 16;
  if (threadIdx.x < 3) {
    float s = 0.f;
    for (int dd = 0; dd < 32; dd++) s += omout[(b*3 + threadIdx.x)*32 + dd];
    sm[threadIdx.x] = s;
  }
  __syncthreads();
  if (threadIdx.x == 0) order3(sm, sord);
  __syncthreads();
  int o0 = sord[0], o1 = sord[1], o2 = sord[2];
  float v0 = out[(size_t)o0*BLD + r];
  float v1 = out[(size_t)o1*BLD + r];
  float v2 = out[(size_t)o2*BLD + r];
  out[r] = v0;
  out[(size_t)BLD + r] = v1;
  out[(size_t)2*BLD + r] = v2;
}

extern "C" void kernel_launch(void* const* d_in, const int* in_sizes, int n_in,
                              void* d_out, int out_size, void* d_ws, size_t ws_size,
                              hipStream_t stream)
{
  const float* x = (const float*)d_in[0];
  float* out = (float*)d_out;
  const size_t NU = (size_t)3 * BLD;
  size_t need = NU*4 + 768*4;
  if (ws_size >= need) {
    float* wsu  = (float*)d_ws;
    float* wsom = wsu + NU;
    vmd_main<true><<<256, 256, 0, stream>>>(x, wsu, wsom);
    vmd_permute<<<1536, 256, 0, stream>>>(wsu, wsom, out);
  } else {
    float* wsom = (float*)d_ws;
    vmd_main<false><<<256, 256, 0, stream>>>(x, out, wsom);
    vmd_inplace<<<2048, 256, 0, stream>>>(out, wsom);
  }
}